// Round 24
// baseline (61.016 us; speedup 1.0000x reference)
//
#include <hip/hip_runtime.h>

#define B 128
#define S 512
#define T 64
#define G 16

typedef short bf16x8 __attribute__((ext_vector_type(8)));
typedef float f32x4 __attribute__((ext_vector_type(4)));
typedef _Float16 h2 __attribute__((ext_vector_type(2)));

__device__ __forceinline__ float rdlane(float v, int l) {
    return __int_as_float(__builtin_amdgcn_readlane(__float_as_int(v), l));
}
__device__ __forceinline__ unsigned cvtpk_bf16(float lo, float hi) {
    unsigned r;
    asm("v_cvt_pk_bf16_f32 %0, %1, %2" : "=v"(r) : "v"(lo), "v"(hi));
    return r;
}
__device__ __forceinline__ float fast_exp2(float x) {
    float r;
    asm("v_exp_f32 %0, %1" : "=v"(r) : "v"(x));
    return r;
}
// A/B fragment k-index for mfma_f32_16x16x32_bf16, SPLIT-HALF mapping
// (validated round 6, absmax=0): e=0..3 -> k=4*gq+e ; e=4..7 -> k=16+4*gq+(e-4)
__device__ __forceinline__ int krow(int kt, int gq, int e) {
    return 32 * kt + ((e >> 2) << 4) + 4 * gq + (e & 3);
}

// ============================================================================
// Phase 1 (r19 structure, SINGLE CHANGE: launch_bounds(64,2) -> (64,4)).
// Measured footprint VGPR_Count=76 fits the 128-unified cap; the 2nd arg is
// MIN WAVES PER EU — declaring 4 provisions 4 waves/SIMD = 16 waves/CU vs
// the observed 4-5/CU residency cap, the last untested single variable.
// Spill tripwire: FETCH > 20MB.
// Step: fixed 2^-7/step scaling folded into d-exponent; C-side diagonal;
// static bf16 E^T fragments; no max tree / cross-lane reduce.
// ============================================================================
template<int GG>
__global__ __launch_bounds__(64, 4)
void crf_chunk_bf(const float* __restrict__ features,
                  const float* __restrict__ mask,
                  const float* __restrict__ transitions,
                  unsigned short* __restrict__ Zout,
                  int* __restrict__ Kout)
{
    constexpr int CLT = S / GG;                // 32
    __shared__ unsigned short relay[T * 68];   // used ONCE at end

    const int lane = threadIdx.x;
    const int b  = blockIdx.x / GG;
    const int g  = blockIdx.x % GG;
    const int c  = lane & 15;
    const int gq = lane >> 4;

    // ---- static A = E^T in bf16 fragments: A[i][k] = exp(W[k][i]) ----
    bf16x8 Ef[4][2];
    #pragma unroll
    for (int rt = 0; rt < 4; ++rt)
      #pragma unroll
      for (int kt = 0; kt < 2; ++kt) {
          unsigned dw[4];
          #pragma unroll
          for (int w = 0; w < 4; ++w) {
              int k0 = krow(kt, gq, 2 * w);     // even e: k(e+1) = k0+1
              float x0 = __expf(transitions[k0       * T + (c + 16*rt)]);
              float x1 = __expf(transitions[(k0 + 1) * T + (c + 16*rt)]);
              dw[w] = cvtpk_bf16(x0, x1);
          }
          uint4 q; q.x = dw[0]; q.y = dw[1]; q.z = dw[2]; q.w = dw[3];
          Ef[rt][kt] = __builtin_bit_cast(bf16x8, q);
      }

    // ---- Z init = identity, in B-fragment layout (bf16 1.0 = 0x3F80) ----
    bf16x8 Bf[2][4];
    #pragma unroll
    for (int kt = 0; kt < 2; ++kt)
      #pragma unroll
      for (int ct = 0; ct < 4; ++ct)
        #pragma unroll
        for (int e = 0; e < 8; ++e)
            Bf[kt][ct][e] = (krow(kt, gq, e) == 16*ct + c) ? (short)0x3F80
                                                           : (short)0;

    const float* fb = features + (size_t)b * S * T;
    const float* mb = mask + (size_t)b * S;
    const int t0 = g * CLT + 1;
    const int t1 = (g == GG - 1) ? S : (t0 + CLT);

    const f32x4 zero4 = {0.f, 0.f, 0.f, 0.f};  // shared C-in for first MFMA

    int ktot = 0;

    // emission/mask prefetch, depth 2; em rows for C-scale: f32x4 at
    // row0 = 16*rt + 4*gq (the C/D rows this lane owns)
    f32x4 emP1[4], emP2[4];
    #pragma unroll
    for (int rt = 0; rt < 4; ++rt) {
        emP1[rt] = *(const f32x4*)(fb + t0 * T + 16*rt + 4*gq);
        emP2[rt] = *(const f32x4*)(fb + min(t0 + 1, S - 1) * T + 16*rt + 4*gq);
    }
    float m1 = mb[t0], m2 = mb[min(t0 + 1, S - 1)];

    for (int t = t0; t < t1; ++t) {
        f32x4 emc[4];
        #pragma unroll
        for (int rt = 0; rt < 4; ++rt) emc[rt] = emP1[rt];
        float mc = m1;
        {   // rotate + prefetch t+2
            int t2 = min(t + 2, S - 1);
            #pragma unroll
            for (int rt = 0; rt < 4; ++rt) {
                emP1[rt] = emP2[rt];
                emP2[rt] = *(const f32x4*)(fb + t2 * T + 16*rt + 4*gq);
            }
            m1 = m2; m2 = mb[t2];
        }

        if (mc != 0.0f) {
            ktot += 7;
            // d4[tr][r] = exp(em[row]) * 2^-7 = exp2(em*log2e - 7)
            f32x4 d4[4];
            #pragma unroll
            for (int rt = 0; rt < 4; ++rt)
                #pragma unroll
                for (int r = 0; r < 4; ++r)
                    d4[rt][r] = fast_exp2(fmaf(emc[rt][r], 1.44269504f, -7.0f));

            // per output-column: 8 MFMAs -> row-scale -> repack (no max)
            #pragma unroll
            for (int ct = 0; ct < 4; ++ct) {
                f32x4 Ct[4];
                #pragma unroll
                for (int tr = 0; tr < 4; ++tr) {
                    f32x4 z = __builtin_amdgcn_mfma_f32_16x16x32_bf16(Ef[tr][0], Bf[0][ct], zero4, 0, 0, 0);
                    z = __builtin_amdgcn_mfma_f32_16x16x32_bf16(Ef[tr][1], Bf[1][ct], z, 0, 0, 0);
                    Ct[tr] = z * d4[tr];
                }
                uint4 q0, q1;
                q0.x = cvtpk_bf16(Ct[0][0], Ct[0][1]);
                q0.y = cvtpk_bf16(Ct[0][2], Ct[0][3]);
                q0.z = cvtpk_bf16(Ct[1][0], Ct[1][1]);
                q0.w = cvtpk_bf16(Ct[1][2], Ct[1][3]);
                q1.x = cvtpk_bf16(Ct[2][0], Ct[2][1]);
                q1.y = cvtpk_bf16(Ct[2][2], Ct[2][3]);
                q1.z = cvtpk_bf16(Ct[3][0], Ct[3][1]);
                q1.w = cvtpk_bf16(Ct[3][2], Ct[3][3]);
                Bf[0][ct] = __builtin_bit_cast(bf16x8, q0);
                Bf[1][ct] = __builtin_bit_cast(bf16x8, q1);
            }
        }
    }

    // ---- ONE-TIME relayout to row-major bf16 Zout via LDS ----
    #pragma unroll
    for (int kt = 0; kt < 2; ++kt)
      #pragma unroll
      for (int ct = 0; ct < 4; ++ct) {
          uint4 q = __builtin_bit_cast(uint4, Bf[kt][ct]);
          int col = 16*ct + c;
          uint2 wa; wa.x = q.x; wa.y = q.y;     // rows 32kt+4gq+0..3
          uint2 wb; wb.x = q.z; wb.y = q.w;     // rows 32kt+16+4gq+0..3
          *(uint2*)&relay[col * 68 + 32*kt      + 4*gq] = wa;
          *(uint2*)&relay[col * 68 + 32*kt + 16 + 4*gq] = wb;
      }
    asm volatile("s_waitcnt lgkmcnt(0)" ::: "memory");

    unsigned short* zo = Zout + ((size_t)(b * GG + g)) * 64 * 64;
    #pragma unroll
    for (int q8 = 0; q8 < 8; ++q8) {
        unsigned dw[4];
        #pragma unroll
        for (int d = 0; d < 4; ++d) {
            unsigned lo = relay[(8*q8 + 2*d    ) * 68 + lane];
            unsigned hi = relay[(8*q8 + 2*d + 1) * 68 + lane];
            dw[d] = lo | (hi << 16);
        }
        uint4 wv; wv.x = dw[0]; wv.y = dw[1]; wv.z = dw[2]; wv.w = dw[3];
        *(uint4*)(zo + (size_t)lane * 64 + 8*q8) = wv;
    }
    if (lane == 0) Kout[b * GG + g] = ktot;
}

// ============================================================================
// Phase 2 (r13/r18-exact): one wave per batch. v <- Z_g v sequentially;
// normalizer = exact pow2 from lane-1's exponent; esum folded at the end.
// ============================================================================
template<int GG>
__global__ __launch_bounds__(64, 1)
void crf_apply(const float* __restrict__ features,
               const int*   __restrict__ labels,
               const float* __restrict__ mask,
               const float* __restrict__ transitions,
               const unsigned short* __restrict__ Zmat,
               const int*   __restrict__ Kscale,
               float*       __restrict__ res)
{
    __shared__ float trans_lds[T * T];
    __shared__ float bcast[2][T];
    const int lane = threadIdx.x;
    const int b = blockIdx.x;

    for (int i = 0; i < T; ++i)
        trans_lds[i * T + lane] = transitions[i * T + lane];
    __syncthreads();

    const float* fb = features + (size_t)b * S * T;
    const int*   lb = labels + (size_t)b * S;
    const float* mb = mask + (size_t)b * S;

    // ---- gold score (lane i handles t = 64*ch + i) ----
    float gold = 0.f;
    #pragma unroll
    for (int ch = 0; ch < S / T; ++ch) {
        int tt = ch * T + lane;
        int tm1 = tt > 0 ? tt - 1 : 0;
        int la = lb[tt], lp = lb[tm1];
        float mt = mb[tt], mp = mb[tm1];
        float em_g = fb[(size_t)tt * T + la];
        float tr_g = trans_lds[lp * T + la];
        gold += em_g * mt + ((tt > 0) ? tr_g * (mp * mt) : 0.f);
    }

    // ---- v init from alpha_0 = em_0, normalized by wave max (one-time) ----
    float a0 = fb[lane];
    float A0 = a0;
    #pragma unroll
    for (int o = 32; o > 0; o >>= 1) A0 = fmaxf(A0, __shfl_xor(A0, o));
    float v = __expf(a0 - A0);

    int esum = 0;

    // double-buffered Z-row loads (lane j holds row j)
    const unsigned short* zb = Zmat + ((size_t)b * GG) * 64 * 64 + (size_t)lane * 64;
    uint4 cur[8], nxt[8];
    #pragma unroll
    for (int i = 0; i < 8; ++i) cur[i] = ((const uint4*)zb)[i];

    for (int g = 0; g < GG; ++g) {
        if (g + 1 < GG) {
            const uint4* zn = (const uint4*)(zb + (size_t)(g + 1) * 64 * 64);
            #pragma unroll
            for (int i = 0; i < 8; ++i) nxt[i] = zn[i];
        }
        const int buf = g & 1;
        bcast[buf][lane] = v;
        asm volatile("s_waitcnt lgkmcnt(0)" ::: "memory");
        f32x4 vb[16];
        #pragma unroll
        for (int q = 0; q < 16; ++q) vb[q] = ((const f32x4*)bcast[buf])[q];

        float ac0 = 0.f, ac1 = 0.f, ac2 = 0.f, ac3 = 0.f;
        #pragma unroll
        for (int i = 0; i < 8; ++i) {
            unsigned zz[4] = {cur[i].x, cur[i].y, cur[i].z, cur[i].w};
            #pragma unroll
            for (int d = 0; d < 4; ++d) {
                int k = i * 8 + d * 2;
                float f0 = __int_as_float(zz[d] << 16);
                float f1 = __int_as_float(zz[d] & 0xFFFF0000u);
                if ((d & 1) == 0) { ac0 = fmaf(f0, vb[k >> 2][k & 3], ac0);
                                    ac1 = fmaf(f1, vb[(k+1) >> 2][(k+1) & 3], ac1); }
                else             { ac2 = fmaf(f0, vb[k >> 2][k & 3], ac2);
                                    ac3 = fmaf(f1, vb[(k+1) >> 2][(k+1) & 3], ac3); }
            }
        }
        float acc = (ac0 + ac1) + (ac2 + ac3);

        // exact pow2 normalizer from lane 1's exponent (lane 0 is PAD -> 0)
        float a1 = fmaxf(rdlane(acc, 1), 1e-30f);
        int e = ((__float_as_int(a1) >> 23) & 0xFF) - 127;
        v = acc * __int_as_float((unsigned)(127 - e) << 23);
        esum += e + Kscale[b * GG + g];

        #pragma unroll
        for (int i = 0; i < 8; ++i) cur[i] = nxt[i];
    }

    float sum = v;
    #pragma unroll
    for (int o = 32; o > 0; o >>= 1) sum += __shfl_xor(sum, o);
    float logZ = __logf(fmaxf(sum, 1e-30f)) + A0 + (float)esum * 0.69314718056f;

    #pragma unroll
    for (int o = 32; o > 0; o >>= 1) gold += __shfl_xor(gold, o);

    if (lane == 0) res[b] = logZ - gold;
}

// ============================================================================
// Fallback: validated round-3 sequential kernel (used if ws too small)
// ============================================================================
__global__ __launch_bounds__(64, 1)
void crf_fwd_seq(const float* __restrict__ features,
                 const int*   __restrict__ labels,
                 const float* __restrict__ mask,
                 const float* __restrict__ transitions,
                 float*       __restrict__ ws)
{
    __shared__ float trans_lds[T * T];
    __shared__ __align__(16) _Float16 ea_lds[2][T];

    const int lane = threadIdx.x;
    const int b    = blockIdx.x;

    for (int i = 0; i < T; ++i)
        trans_lds[i * T + lane] = transitions[i * T + lane];
    __syncthreads();

    h2 etr[T / 2];
    #pragma unroll
    for (int k = 0; k < T / 2; ++k) {
        etr[k].x = (_Float16)__expf(trans_lds[(2 * k + 0) * T + lane]);
        etr[k].y = (_Float16)__expf(trans_lds[(2 * k + 1) * T + lane]);
    }

    const float* fb = features + (size_t)b * S * T;
    const float* mb = mask + (size_t)b * S;
    const int*   lb = labels + (size_t)b * S;

    float alpha = fb[lane];
    float gold_part = 0.f;
    float M = 0.f;

    float em_n1 = fb[1 * T + lane];
    float em_n2 = fb[2 * T + lane];
    float em_n3 = fb[3 * T + lane];

    int   lab_c = lb[lane];
    int   lab_p = lb[lane > 0 ? lane - 1 : 0];
    float m_c   = mb[lane];
    float m_p   = mb[lane > 0 ? lane - 1 : 0];

    for (int ch = 0; ch < S / T; ++ch) {
        const int base = ch * T;
        const int tt   = base + lane;

        const int   glab  = lab_c;
        const int   glabp = lab_p;
        const float gmc   = m_c;
        const float gmp   = m_p;
        const float mreg  = m_c;

        float em_g = fb[(size_t)tt * T + glab];
        float tr_g = trans_lds[glabp * T + glab];

        {
            int tn  = tt + T;  if (tn > S - 1) tn = S - 1;
            int tnp = tn - 1;  if (tnp < 0) tnp = 0;
            lab_c = lb[tn]; lab_p = lb[tnp];
            m_c   = mb[tn]; m_p   = mb[tnp];
        }

        const int i0 = (ch == 0) ? 1 : 0;
        #pragma unroll 4
        for (int i = i0; i < T; ++i) {
            const int t = base + i;
            float em = em_n1;
            em_n1 = em_n2; em_n2 = em_n3;
            int tn = t + 3; if (tn > S - 1) tn = S - 1;
            em_n3 = fb[tn * T + lane];

            float ea = __expf(alpha - M);
            ea_lds[t & 1][lane] = (_Float16)ea;
            asm volatile("s_waitcnt lgkmcnt(0)" ::: "memory");

            const uint4* ep = (const uint4*)&ea_lds[t & 1][0];
            float a0 = 0.f, a1 = 0.f, a2 = 0.f, a3 = 0.f;
            #pragma unroll
            for (int q = 0; q < 8; ++q) {
                uint4 r = ep[q];
                a0 = __builtin_amdgcn_fdot2(__builtin_bit_cast(h2, r.x), etr[4 * q + 0], a0, false);
                a1 = __builtin_amdgcn_fdot2(__builtin_bit_cast(h2, r.y), etr[4 * q + 1], a1, false);
                a2 = __builtin_amdgcn_fdot2(__builtin_bit_cast(h2, r.z), etr[4 * q + 2], a2, false);
                a3 = __builtin_amdgcn_fdot2(__builtin_bit_cast(h2, r.w), etr[4 * q + 3], a3, false);
            }
            float s = (a0 + a1) + (a2 + a3);

            float m_t = rdlane(mreg, i);
            float s1  = rdlane(s, 1);
            float em1 = rdlane(em, 1);
            float Mn  = M + __logf(s1) + em1;

            float val = M + __logf(s) + em;
            val = fmaxf(val, -1e30f);
            alpha = val * m_t + alpha * (1.f - m_t);
            M     = (m_t > 0.5f) ? Mn : M;
        }

        float valid = (tt > 0) ? 1.f : 0.f;
        gold_part += em_g * gmc + tr_g * (gmp * gmc) * valid;
    }

    float M2 = alpha;
    #pragma unroll
    for (int o = 32; o > 0; o >>= 1) M2 = fmaxf(M2, __shfl_xor(M2, o));
    float e2 = __expf(alpha - M2);
    #pragma unroll
    for (int o = 32; o > 0; o >>= 1) e2 += __shfl_xor(e2, o);
    float logZ = M2 + __logf(e2);

    #pragma unroll
    for (int o = 32; o > 0; o >>= 1) gold_part += __shfl_xor(gold_part, o);

    if (lane == 0) ws[b] = logZ - gold_part;
}

// Deterministic final mean over B=128 per-batch results.
__global__ __launch_bounds__(128)
void crf_reduce(const float* __restrict__ ws, float* __restrict__ out)
{
    const int tid = threadIdx.x;
    float v = ws[tid];
    #pragma unroll
    for (int o = 32; o > 0; o >>= 1) v += __shfl_xor(v, o);

    __shared__ float partial[2];
    if ((tid & 63) == 0) partial[tid >> 6] = v;
    __syncthreads();
    if (tid == 0) out[0] = (partial[0] + partial[1]) * (1.0f / (float)B);
}

extern "C" void kernel_launch(void* const* d_in, const int* in_sizes, int n_in,
                              void* d_out, int out_size, void* d_ws, size_t ws_size,
                              hipStream_t stream)
{
    const float* features    = (const float*)d_in[0]; // (B,S,T) f32
    const int*   labels      = (const int*)  d_in[1]; // (B,S) int
    const float* mask        = (const float*)d_in[2]; // (B,S) f32
    const float* transitions = (const float*)d_in[3]; // (T,T) f32
    float* out = (float*)d_out;

    const size_t zbytes = (size_t)B * G * 64 * 64 * sizeof(unsigned short); // 16 MB
    const size_t kbytes = (size_t)B * G * sizeof(int);
    const size_t need   = zbytes + kbytes + (size_t)B * sizeof(float);

    if (ws_size >= need) {
        unsigned short* Zmat = (unsigned short*)d_ws;
        int*   Ks  = (int*)((char*)d_ws + zbytes);
        float* res = (float*)((char*)d_ws + zbytes + kbytes);
        crf_chunk_bf<G><<<dim3(B * G), dim3(64), 0, stream>>>(features, mask, transitions, Zmat, Ks);
        crf_apply<G><<<dim3(B), dim3(64), 0, stream>>>(features, labels, mask, transitions, Zmat, Ks, res);
        crf_reduce<<<dim3(1), dim3(128), 0, stream>>>(res, out);
    } else {
        float* res = (float*)d_ws;
        crf_fwd_seq<<<dim3(B), dim3(64), 0, stream>>>(features, labels, mask, transitions, res);
        crf_reduce<<<dim3(1), dim3(128), 0, stream>>>(res, out);
    }
}

// Round 25
// 57.016 us; speedup vs baseline: 1.0702x; 1.0702x over previous
//
#include <hip/hip_runtime.h>

#define B 128
#define S 512
#define T 64
#define G 16

typedef short bf16x8 __attribute__((ext_vector_type(8)));
typedef float f32x4 __attribute__((ext_vector_type(4)));
typedef _Float16 h2 __attribute__((ext_vector_type(2)));

__device__ __forceinline__ float rdlane(float v, int l) {
    return __int_as_float(__builtin_amdgcn_readlane(__float_as_int(v), l));
}
__device__ __forceinline__ unsigned cvtpk_bf16(float lo, float hi) {
    unsigned r;
    asm("v_cvt_pk_bf16_f32 %0, %1, %2" : "=v"(r) : "v"(lo), "v"(hi));
    return r;
}
__device__ __forceinline__ float fast_exp2(float x) {
    float r;
    asm("v_exp_f32 %0, %1" : "=v"(r) : "v"(x));
    return r;
}
// A/B fragment k-index for mfma_f32_16x16x32_bf16, SPLIT-HALF mapping
// (validated round 6, absmax=0): e=0..3 -> k=4*gq+e ; e=4..7 -> k=16+4*gq+(e-4)
__device__ __forceinline__ int krow(int kt, int gq, int e) {
    return 32 * kt + ((e >> 2) << 4) + 4 * gq + (e & 3);
}

// ============================================================================
// FINAL (r19/r23 configuration — best measured, 57.2/57.4us, reproduced).
// Phase 1: one wave per (b, chunk); Z_g = prod (D_t E^T) in bf16 via chained
// 64x64x64 MFMAs; FIXED 2^-7/step pow2 scaling folded into the d-exponent
// (E re-mixes rows each step so deviations don't accumulate; |log2 Z| ~ 26
// << 127); C-side diagonal; static bf16 E^T fragments; launch_bounds(64,2).
// Evidence (r9-r24): chunk wall ~48-54us invariant across G, wave-grouping,
// launch-bounds, AGPR/VGPR acc, column-split, prefetch depth; limited by
// scheduler residency (~5 waves/CU on 1-wave wg) x serial chain latency.
// Both cliffs measured: >3 waves/EU spills (r11/r15/r22/r24), fewer waves
// starve (r19). MFMA 23% / HBM 6% of peak: unreachable within this
// dependency structure.
// ============================================================================
template<int GG>
__global__ __launch_bounds__(64, 2)
void crf_chunk_bf(const float* __restrict__ features,
                  const float* __restrict__ mask,
                  const float* __restrict__ transitions,
                  unsigned short* __restrict__ Zout,
                  int* __restrict__ Kout)
{
    constexpr int CLT = S / GG;                // 32
    __shared__ unsigned short relay[T * 68];   // used ONCE at end

    const int lane = threadIdx.x;
    const int b  = blockIdx.x / GG;
    const int g  = blockIdx.x % GG;
    const int c  = lane & 15;
    const int gq = lane >> 4;

    // ---- static A = E^T in bf16 fragments: A[i][k] = exp(W[k][i]) ----
    bf16x8 Ef[4][2];
    #pragma unroll
    for (int rt = 0; rt < 4; ++rt)
      #pragma unroll
      for (int kt = 0; kt < 2; ++kt) {
          unsigned dw[4];
          #pragma unroll
          for (int w = 0; w < 4; ++w) {
              int k0 = krow(kt, gq, 2 * w);     // even e: k(e+1) = k0+1
              float x0 = __expf(transitions[k0       * T + (c + 16*rt)]);
              float x1 = __expf(transitions[(k0 + 1) * T + (c + 16*rt)]);
              dw[w] = cvtpk_bf16(x0, x1);
          }
          uint4 q; q.x = dw[0]; q.y = dw[1]; q.z = dw[2]; q.w = dw[3];
          Ef[rt][kt] = __builtin_bit_cast(bf16x8, q);
      }

    // ---- Z init = identity, in B-fragment layout (bf16 1.0 = 0x3F80) ----
    bf16x8 Bf[2][4];
    #pragma unroll
    for (int kt = 0; kt < 2; ++kt)
      #pragma unroll
      for (int ct = 0; ct < 4; ++ct)
        #pragma unroll
        for (int e = 0; e < 8; ++e)
            Bf[kt][ct][e] = (krow(kt, gq, e) == 16*ct + c) ? (short)0x3F80
                                                           : (short)0;

    const float* fb = features + (size_t)b * S * T;
    const float* mb = mask + (size_t)b * S;
    const int t0 = g * CLT + 1;
    const int t1 = (g == GG - 1) ? S : (t0 + CLT);

    const f32x4 zero4 = {0.f, 0.f, 0.f, 0.f};  // shared C-in for first MFMA

    int ktot = 0;

    // emission/mask prefetch, depth 2; em rows for C-scale: f32x4 at
    // row0 = 16*rt + 4*gq (the C/D rows this lane owns)
    f32x4 emP1[4], emP2[4];
    #pragma unroll
    for (int rt = 0; rt < 4; ++rt) {
        emP1[rt] = *(const f32x4*)(fb + t0 * T + 16*rt + 4*gq);
        emP2[rt] = *(const f32x4*)(fb + min(t0 + 1, S - 1) * T + 16*rt + 4*gq);
    }
    float m1 = mb[t0], m2 = mb[min(t0 + 1, S - 1)];

    for (int t = t0; t < t1; ++t) {
        f32x4 emc[4];
        #pragma unroll
        for (int rt = 0; rt < 4; ++rt) emc[rt] = emP1[rt];
        float mc = m1;
        {   // rotate + prefetch t+2
            int t2 = min(t + 2, S - 1);
            #pragma unroll
            for (int rt = 0; rt < 4; ++rt) {
                emP1[rt] = emP2[rt];
                emP2[rt] = *(const f32x4*)(fb + t2 * T + 16*rt + 4*gq);
            }
            m1 = m2; m2 = mb[t2];
        }

        if (mc != 0.0f) {
            ktot += 7;
            // d4[tr][r] = exp(em[row]) * 2^-7 = exp2(em*log2e - 7)
            f32x4 d4[4];
            #pragma unroll
            for (int rt = 0; rt < 4; ++rt)
                #pragma unroll
                for (int r = 0; r < 4; ++r)
                    d4[rt][r] = fast_exp2(fmaf(emc[rt][r], 1.44269504f, -7.0f));

            // per output-column: 8 MFMAs -> row-scale -> repack (no max)
            #pragma unroll
            for (int ct = 0; ct < 4; ++ct) {
                f32x4 Ct[4];
                #pragma unroll
                for (int tr = 0; tr < 4; ++tr) {
                    f32x4 z = __builtin_amdgcn_mfma_f32_16x16x32_bf16(Ef[tr][0], Bf[0][ct], zero4, 0, 0, 0);
                    z = __builtin_amdgcn_mfma_f32_16x16x32_bf16(Ef[tr][1], Bf[1][ct], z, 0, 0, 0);
                    Ct[tr] = z * d4[tr];
                }
                uint4 q0, q1;
                q0.x = cvtpk_bf16(Ct[0][0], Ct[0][1]);
                q0.y = cvtpk_bf16(Ct[0][2], Ct[0][3]);
                q0.z = cvtpk_bf16(Ct[1][0], Ct[1][1]);
                q0.w = cvtpk_bf16(Ct[1][2], Ct[1][3]);
                q1.x = cvtpk_bf16(Ct[2][0], Ct[2][1]);
                q1.y = cvtpk_bf16(Ct[2][2], Ct[2][3]);
                q1.z = cvtpk_bf16(Ct[3][0], Ct[3][1]);
                q1.w = cvtpk_bf16(Ct[3][2], Ct[3][3]);
                Bf[0][ct] = __builtin_bit_cast(bf16x8, q0);
                Bf[1][ct] = __builtin_bit_cast(bf16x8, q1);
            }
        }
    }

    // ---- ONE-TIME relayout to row-major bf16 Zout via LDS ----
    #pragma unroll
    for (int kt = 0; kt < 2; ++kt)
      #pragma unroll
      for (int ct = 0; ct < 4; ++ct) {
          uint4 q = __builtin_bit_cast(uint4, Bf[kt][ct]);
          int col = 16*ct + c;
          uint2 wa; wa.x = q.x; wa.y = q.y;     // rows 32kt+4gq+0..3
          uint2 wb; wb.x = q.z; wb.y = q.w;     // rows 32kt+16+4gq+0..3
          *(uint2*)&relay[col * 68 + 32*kt      + 4*gq] = wa;
          *(uint2*)&relay[col * 68 + 32*kt + 16 + 4*gq] = wb;
      }
    asm volatile("s_waitcnt lgkmcnt(0)" ::: "memory");

    unsigned short* zo = Zout + ((size_t)(b * GG + g)) * 64 * 64;
    #pragma unroll
    for (int q8 = 0; q8 < 8; ++q8) {
        unsigned dw[4];
        #pragma unroll
        for (int d = 0; d < 4; ++d) {
            unsigned lo = relay[(8*q8 + 2*d    ) * 68 + lane];
            unsigned hi = relay[(8*q8 + 2*d + 1) * 68 + lane];
            dw[d] = lo | (hi << 16);
        }
        uint4 wv; wv.x = dw[0]; wv.y = dw[1]; wv.z = dw[2]; wv.w = dw[3];
        *(uint4*)(zo + (size_t)lane * 64 + 8*q8) = wv;
    }
    if (lane == 0) Kout[b * GG + g] = ktot;
}

// ============================================================================
// Phase 2 (r13/r18-exact): one wave per batch. v <- Z_g v sequentially;
// normalizer = exact pow2 from lane-1's exponent; esum folded at the end.
// ============================================================================
template<int GG>
__global__ __launch_bounds__(64, 1)
void crf_apply(const float* __restrict__ features,
               const int*   __restrict__ labels,
               const float* __restrict__ mask,
               const float* __restrict__ transitions,
               const unsigned short* __restrict__ Zmat,
               const int*   __restrict__ Kscale,
               float*       __restrict__ res)
{
    __shared__ float trans_lds[T * T];
    __shared__ float bcast[2][T];
    const int lane = threadIdx.x;
    const int b = blockIdx.x;

    for (int i = 0; i < T; ++i)
        trans_lds[i * T + lane] = transitions[i * T + lane];
    __syncthreads();

    const float* fb = features + (size_t)b * S * T;
    const int*   lb = labels + (size_t)b * S;
    const float* mb = mask + (size_t)b * S;

    // ---- gold score (lane i handles t = 64*ch + i) ----
    float gold = 0.f;
    #pragma unroll
    for (int ch = 0; ch < S / T; ++ch) {
        int tt = ch * T + lane;
        int tm1 = tt > 0 ? tt - 1 : 0;
        int la = lb[tt], lp = lb[tm1];
        float mt = mb[tt], mp = mb[tm1];
        float em_g = fb[(size_t)tt * T + la];
        float tr_g = trans_lds[lp * T + la];
        gold += em_g * mt + ((tt > 0) ? tr_g * (mp * mt) : 0.f);
    }

    // ---- v init from alpha_0 = em_0, normalized by wave max (one-time) ----
    float a0 = fb[lane];
    float A0 = a0;
    #pragma unroll
    for (int o = 32; o > 0; o >>= 1) A0 = fmaxf(A0, __shfl_xor(A0, o));
    float v = __expf(a0 - A0);

    int esum = 0;

    // double-buffered Z-row loads (lane j holds row j)
    const unsigned short* zb = Zmat + ((size_t)b * GG) * 64 * 64 + (size_t)lane * 64;
    uint4 cur[8], nxt[8];
    #pragma unroll
    for (int i = 0; i < 8; ++i) cur[i] = ((const uint4*)zb)[i];

    for (int g = 0; g < GG; ++g) {
        if (g + 1 < GG) {
            const uint4* zn = (const uint4*)(zb + (size_t)(g + 1) * 64 * 64);
            #pragma unroll
            for (int i = 0; i < 8; ++i) nxt[i] = zn[i];
        }
        const int buf = g & 1;
        bcast[buf][lane] = v;
        asm volatile("s_waitcnt lgkmcnt(0)" ::: "memory");
        f32x4 vb[16];
        #pragma unroll
        for (int q = 0; q < 16; ++q) vb[q] = ((const f32x4*)bcast[buf])[q];

        float ac0 = 0.f, ac1 = 0.f, ac2 = 0.f, ac3 = 0.f;
        #pragma unroll
        for (int i = 0; i < 8; ++i) {
            unsigned zz[4] = {cur[i].x, cur[i].y, cur[i].z, cur[i].w};
            #pragma unroll
            for (int d = 0; d < 4; ++d) {
                int k = i * 8 + d * 2;
                float f0 = __int_as_float(zz[d] << 16);
                float f1 = __int_as_float(zz[d] & 0xFFFF0000u);
                if ((d & 1) == 0) { ac0 = fmaf(f0, vb[k >> 2][k & 3], ac0);
                                    ac1 = fmaf(f1, vb[(k+1) >> 2][(k+1) & 3], ac1); }
                else             { ac2 = fmaf(f0, vb[k >> 2][k & 3], ac2);
                                    ac3 = fmaf(f1, vb[(k+1) >> 2][(k+1) & 3], ac3); }
            }
        }
        float acc = (ac0 + ac1) + (ac2 + ac3);

        // exact pow2 normalizer from lane 1's exponent (lane 0 is PAD -> 0)
        float a1 = fmaxf(rdlane(acc, 1), 1e-30f);
        int e = ((__float_as_int(a1) >> 23) & 0xFF) - 127;
        v = acc * __int_as_float((unsigned)(127 - e) << 23);
        esum += e + Kscale[b * GG + g];

        #pragma unroll
        for (int i = 0; i < 8; ++i) cur[i] = nxt[i];
    }

    float sum = v;
    #pragma unroll
    for (int o = 32; o > 0; o >>= 1) sum += __shfl_xor(sum, o);
    float logZ = __logf(fmaxf(sum, 1e-30f)) + A0 + (float)esum * 0.69314718056f;

    #pragma unroll
    for (int o = 32; o > 0; o >>= 1) gold += __shfl_xor(gold, o);

    if (lane == 0) res[b] = logZ - gold;
}

// ============================================================================
// Fallback: validated round-3 sequential kernel (used if ws too small)
// ============================================================================
__global__ __launch_bounds__(64, 1)
void crf_fwd_seq(const float* __restrict__ features,
                 const int*   __restrict__ labels,
                 const float* __restrict__ mask,
                 const float* __restrict__ transitions,
                 float*       __restrict__ ws)
{
    __shared__ float trans_lds[T * T];
    __shared__ __align__(16) _Float16 ea_lds[2][T];

    const int lane = threadIdx.x;
    const int b    = blockIdx.x;

    for (int i = 0; i < T; ++i)
        trans_lds[i * T + lane] = transitions[i * T + lane];
    __syncthreads();

    h2 etr[T / 2];
    #pragma unroll
    for (int k = 0; k < T / 2; ++k) {
        etr[k].x = (_Float16)__expf(trans_lds[(2 * k + 0) * T + lane]);
        etr[k].y = (_Float16)__expf(trans_lds[(2 * k + 1) * T + lane]);
    }

    const float* fb = features + (size_t)b * S * T;
    const float* mb = mask + (size_t)b * S;
    const int*   lb = labels + (size_t)b * S;

    float alpha = fb[lane];
    float gold_part = 0.f;
    float M = 0.f;

    float em_n1 = fb[1 * T + lane];
    float em_n2 = fb[2 * T + lane];
    float em_n3 = fb[3 * T + lane];

    int   lab_c = lb[lane];
    int   lab_p = lb[lane > 0 ? lane - 1 : 0];
    float m_c   = mb[lane];
    float m_p   = mb[lane > 0 ? lane - 1 : 0];

    for (int ch = 0; ch < S / T; ++ch) {
        const int base = ch * T;
        const int tt   = base + lane;

        const int   glab  = lab_c;
        const int   glabp = lab_p;
        const float gmc   = m_c;
        const float gmp   = m_p;
        const float mreg  = m_c;

        float em_g = fb[(size_t)tt * T + glab];
        float tr_g = trans_lds[glabp * T + glab];

        {
            int tn  = tt + T;  if (tn > S - 1) tn = S - 1;
            int tnp = tn - 1;  if (tnp < 0) tnp = 0;
            lab_c = lb[tn]; lab_p = lb[tnp];
            m_c   = mb[tn]; m_p   = mb[tnp];
        }

        const int i0 = (ch == 0) ? 1 : 0;
        #pragma unroll 4
        for (int i = i0; i < T; ++i) {
            const int t = base + i;
            float em = em_n1;
            em_n1 = em_n2; em_n2 = em_n3;
            int tn = t + 3; if (tn > S - 1) tn = S - 1;
            em_n3 = fb[tn * T + lane];

            float ea = __expf(alpha - M);
            ea_lds[t & 1][lane] = (_Float16)ea;
            asm volatile("s_waitcnt lgkmcnt(0)" ::: "memory");

            const uint4* ep = (const uint4*)&ea_lds[t & 1][0];
            float a0 = 0.f, a1 = 0.f, a2 = 0.f, a3 = 0.f;
            #pragma unroll
            for (int q = 0; q < 8; ++q) {
                uint4 r = ep[q];
                a0 = __builtin_amdgcn_fdot2(__builtin_bit_cast(h2, r.x), etr[4 * q + 0], a0, false);
                a1 = __builtin_amdgcn_fdot2(__builtin_bit_cast(h2, r.y), etr[4 * q + 1], a1, false);
                a2 = __builtin_amdgcn_fdot2(__builtin_bit_cast(h2, r.z), etr[4 * q + 2], a2, false);
                a3 = __builtin_amdgcn_fdot2(__builtin_bit_cast(h2, r.w), etr[4 * q + 3], a3, false);
            }
            float s = (a0 + a1) + (a2 + a3);

            float m_t = rdlane(mreg, i);
            float s1  = rdlane(s, 1);
            float em1 = rdlane(em, 1);
            float Mn  = M + __logf(s1) + em1;

            float val = M + __logf(s) + em;
            val = fmaxf(val, -1e30f);
            alpha = val * m_t + alpha * (1.f - m_t);
            M     = (m_t > 0.5f) ? Mn : M;
        }

        float valid = (tt > 0) ? 1.f : 0.f;
        gold_part += em_g * gmc + tr_g * (gmp * gmc) * valid;
    }

    float M2 = alpha;
    #pragma unroll
    for (int o = 32; o > 0; o >>= 1) M2 = fmaxf(M2, __shfl_xor(M2, o));
    float e2 = __expf(alpha - M2);
    #pragma unroll
    for (int o = 32; o > 0; o >>= 1) e2 += __shfl_xor(e2, o);
    float logZ = M2 + __logf(e2);

    #pragma unroll
    for (int o = 32; o > 0; o >>= 1) gold_part += __shfl_xor(gold_part, o);

    if (lane == 0) ws[b] = logZ - gold_part;
}

// Deterministic final mean over B=128 per-batch results.
__global__ __launch_bounds__(128)
void crf_reduce(const float* __restrict__ ws, float* __restrict__ out)
{
    const int tid = threadIdx.x;
    float v = ws[tid];
    #pragma unroll
    for (int o = 32; o > 0; o >>= 1) v += __shfl_xor(v, o);

    __shared__ float partial[2];
    if ((tid & 63) == 0) partial[tid >> 6] = v;
    __syncthreads();
    if (tid == 0) out[0] = (partial[0] + partial[1]) * (1.0f / (float)B);
}

extern "C" void kernel_launch(void* const* d_in, const int* in_sizes, int n_in,
                              void* d_out, int out_size, void* d_ws, size_t ws_size,
                              hipStream_t stream)
{
    const float* features    = (const float*)d_in[0]; // (B,S,T) f32
    const int*   labels      = (const int*)  d_in[1]; // (B,S) int
    const float* mask        = (const float*)d_in[2]; // (B,S) f32
    const float* transitions = (const float*)d_in[3]; // (T,T) f32
    float* out = (float*)d_out;

    const size_t zbytes = (size_t)B * G * 64 * 64 * sizeof(unsigned short); // 16 MB
    const size_t kbytes = (size_t)B * G * sizeof(int);
    const size_t need   = zbytes + kbytes + (size_t)B * sizeof(float);

    if (ws_size >= need) {
        unsigned short* Zmat = (unsigned short*)d_ws;
        int*   Ks  = (int*)((char*)d_ws + zbytes);
        float* res = (float*)((char*)d_ws + zbytes + kbytes);
        crf_chunk_bf<G><<<dim3(B * G), dim3(64), 0, stream>>>(features, mask, transitions, Zmat, Ks);
        crf_apply<G><<<dim3(B), dim3(64), 0, stream>>>(features, labels, mask, transitions, Zmat, Ks, res);
        crf_reduce<<<dim3(1), dim3(128), 0, stream>>>(res, out);
    } else {
        float* res = (float*)d_ws;
        crf_fwd_seq<<<dim3(B), dim3(64), 0, stream>>>(features, labels, mask, transitions, res);
        crf_reduce<<<dim3(1), dim3(128), 0, stream>>>(res, out);
    }
}